// Round 9
// baseline (132.277 us; speedup 1.0000x reference)
//
#include <hip/hip_runtime.h>
#include <hip/hip_bf16.h>

// B=4, S=2048, D=512, H=8, DH=64
// m97-structure 128x128 LDS-staged GEMMs (global_load_lds w16 + XOR swizzle).
// flash v6: swapped-operand QK^T (mfma(K,Q) -> S^T), 32x32x16 MFMA, P in-register
// via bf16x2 packs + v_permlane32_swap_b32; flat softmax (tril zeros pin max ~0 ->
// p = exp2(x)); NO LDS in main loop: K/V fragments read global->VGPR (L1/L2
// resident), no barriers; each q-tile's KV sweep split across 2 waves (flat
// softmax => partials add), combined once via LDS; masked tail via V suffix sums.

typedef __bf16 bf16;
typedef __bf16 bf16x8 __attribute__((ext_vector_type(8)));
typedef __bf16 bf16x4v __attribute__((ext_vector_type(4)));
typedef __bf16 bf16x2 __attribute__((ext_vector_type(2)));
typedef float f32x4 __attribute__((ext_vector_type(4)));
typedef float f32x16 __attribute__((ext_vector_type(16)));
typedef unsigned int u32;
typedef u32 u32x4 __attribute__((ext_vector_type(4)));

#define S_LEN 2048
#define DMODEL 512
// log2(e)/sqrt(512): Q pre-scale so softmax exp is a bare exp2
#define QSCALE 0.06375870914f

#define GLDS(g, l) __builtin_amdgcn_global_load_lds(                  \
    (const __attribute__((address_space(1))) void*)(g),               \
    (__attribute__((address_space(3))) void*)(l), 16, 0, 0)

#define PSWAP(a, b) asm volatile("v_permlane32_swap_b32 %0, %1" : "+v"(a), "+v"(b))

// One launch: embed (1,048,576 f4) then Wq,Wk,Wv,Wo (65,536 f4 each).
__global__ __launch_bounds__(256) void cast_all(
    const float* __restrict__ embed, const float* __restrict__ Wq,
    const float* __restrict__ Wk, const float* __restrict__ Wv,
    const float* __restrict__ Wo,
    bf16* __restrict__ Eb, bf16* __restrict__ Wqkv, bf16* __restrict__ Wob) {
  int i = blockIdx.x * 256 + threadIdx.x;
  const float* src;
  bf16* dst;
  int il;
  if (i < 1048576) {
    src = embed; dst = Eb; il = i;
  } else {
    int j = i - 1048576;
    int w = j >> 16;
    il = j & 65535;
    src = (w == 0) ? Wq : (w == 1) ? Wk : (w == 2) ? Wv : Wo;
    dst = (w == 3) ? Wob : Wqkv + (size_t)w * 262144;
  }
  float4 v = reinterpret_cast<const float4*>(src)[il];
  bf16x4v o;
  o[0] = (bf16)v.x; o[1] = (bf16)v.y; o[2] = (bf16)v.z; o[3] = (bf16)v.w;
  *reinterpret_cast<bf16x4v*>(dst + (size_t)il * 4) = o;
}

// ---- 128x128 tile GEMM core: C = A[M,512] * Bw[N,512]^T, K=512, BK=64 ----
__device__ __forceinline__ void gemm128_core(
    const bf16* __restrict__ A, const bf16* __restrict__ Bw,
    int row0, int col0, bf16* As, bf16* Bs, f32x4 (&acc)[4][4]) {
  int tid = threadIdx.x;
  int w = tid >> 6, l = tid & 63, lr = l & 15, lg = l >> 4;
  int wr = w >> 1, wc = w & 1;

  int srow = w * 8 + (l >> 3);
  int scol = ((l & 7) ^ (srow & 7)) << 3;
  const bf16* ga = A + (size_t)(row0 + srow) * DMODEL + scol;
  const bf16* gb = Bw + (size_t)(col0 + srow) * DMODEL + scol;
  char* asb = (char*)As;
  char* bsb = (char*)Bs;
  int sbase = w * 1024;

  int aoff[4], boff[4];
#pragma unroll
  for (int m = 0; m < 4; ++m) {
    aoff[m] = (wr * 64 + m * 16 + lr) * 128 + (((lg ^ (lr & 7))) << 4);
    boff[m] = (wc * 64 + m * 16 + lr) * 128 + (((lg ^ (lr & 7))) << 4);
  }

  for (int k0 = 0; k0 < DMODEL; k0 += 64) {
#pragma unroll
    for (int qt = 0; qt < 4; ++qt) {
      GLDS(ga + (size_t)qt * 32 * DMODEL, asb + qt * 4096 + sbase);
      GLDS(gb + (size_t)qt * 32 * DMODEL, bsb + qt * 4096 + sbase);
    }
    ga += 64; gb += 64;
    __syncthreads();

    bf16x8 af[2][4], bfv[2][4];
#pragma unroll
    for (int m = 0; m < 4; ++m) {
      af[0][m] = *(const bf16x8*)(asb + aoff[m]);
      af[1][m] = *(const bf16x8*)(asb + (aoff[m] ^ 0x40));
      bfv[0][m] = *(const bf16x8*)(bsb + boff[m]);
      bfv[1][m] = *(const bf16x8*)(bsb + (boff[m] ^ 0x40));
    }
#pragma unroll
    for (int m = 0; m < 4; ++m)
#pragma unroll
      for (int n = 0; n < 4; ++n) {
        acc[m][n] = __builtin_amdgcn_mfma_f32_16x16x32_bf16(af[0][m], bfv[0][n], acc[m][n], 0, 0, 0);
        acc[m][n] = __builtin_amdgcn_mfma_f32_16x16x32_bf16(af[1][m], bfv[1][n], acc[m][n], 0, 0, 0);
      }
    __syncthreads();
  }
}

// Fused QKV GEMM: Wqkv[1536][512]; col-tiles 0-3 = Q, 4-7 = K, 8-11 = V.
__global__ __launch_bounds__(256) void gemm_qkv(
    const bf16* __restrict__ A, const bf16* __restrict__ Wqkv,
    const float* __restrict__ bq, const float* __restrict__ bk, const float* __restrict__ bv,
    bf16* __restrict__ Qb, bf16* __restrict__ Kb, bf16* __restrict__ Vt) {
  __shared__ __align__(16) bf16 As[128 * 64];
  __shared__ __align__(16) bf16 Bs[128 * 64];
  int row0 = blockIdx.x * 128, col0 = blockIdx.y * 128;
  f32x4 acc[4][4] = {};
  gemm128_core(A, Wqkv, row0, col0, As, Bs, acc);

  int tid = threadIdx.x;
  int w = tid >> 6, l = tid & 63, lr = l & 15, lg = l >> 4;
  int wr = w >> 1, wc = w & 1;
  int z2 = col0 >> 9;  // 0=Q 1=K 2=V (uniform per block)
  if (z2 < 2) {
    bf16* O = z2 ? Kb : Qb;
    const float* bias = z2 ? bk : bq;
    float qs = z2 ? 1.0f : QSCALE;
#pragma unroll
    for (int n = 0; n < 4; ++n) {
      int cg = (col0 & 511) + wc * 64 + n * 16 + lr;
      float bi = bias[cg];
#pragma unroll
      for (int m = 0; m < 4; ++m) {
        int rg = row0 + wr * 64 + m * 16 + lg * 4;
#pragma unroll
        for (int r = 0; r < 4; ++r)
          O[(size_t)(rg + r) * DMODEL + cg] = (bf16)((acc[m][n][r] + bi) * qs);
      }
    }
  } else {
    // V: store transposed Vt[b][h][e][s]
#pragma unroll
    for (int n = 0; n < 4; ++n) {
      int ep = (col0 & 511) + wc * 64 + n * 16 + lr;
      int h = ep >> 6, e = ep & 63;
      float bi = bv[ep];
#pragma unroll
      for (int m = 0; m < 4; ++m) {
        int rg = row0 + wr * 64 + m * 16 + lg * 4;
        int b = rg >> 11, s0 = rg & 2047;
        bf16x4v pk;
#pragma unroll
        for (int r = 0; r < 4; ++r) pk[r] = (bf16)(acc[m][n][r] + bi);
        *(bf16x4v*)(Vt + ((size_t)((b * 8 + h) * 64 + e)) * S_LEN + s0) = pk;
      }
    }
  }
}

// Wo GEMM + bias + residual, bf16 out (LN reads bf16).
__global__ __launch_bounds__(256) void gemm_wo(
    const bf16* __restrict__ A, const bf16* __restrict__ W,
    const float* __restrict__ bo, const float* __restrict__ embed,
    bf16* __restrict__ X) {
  __shared__ __align__(16) bf16 As[128 * 64];
  __shared__ __align__(16) bf16 Bs[128 * 64];
  int row0 = blockIdx.x * 128, col0 = blockIdx.y * 128;
  f32x4 acc[4][4] = {};
  gemm128_core(A, W, row0, col0, As, Bs, acc);

  int tid = threadIdx.x;
  int w = tid >> 6, l = tid & 63, lr = l & 15, lg = l >> 4;
  int wr = w >> 1, wc = w & 1;
#pragma unroll
  for (int n = 0; n < 4; ++n) {
    int cg = col0 + wc * 64 + n * 16 + lr;
    float bi = bo[cg];
#pragma unroll
    for (int m = 0; m < 4; ++m) {
      int rg = row0 + wr * 64 + m * 16 + lg * 4;
#pragma unroll
      for (int r = 0; r < 4; ++r)
        X[(size_t)(rg + r) * DMODEL + cg] =
            (bf16)(acc[m][n][r] + bi + embed[(size_t)(rg + r) * DMODEL + cg]);
    }
  }
}

// SUF[bh][j][e] = sum_{t >= 16j} V[t][e], j = 0..128 (SUF[128]=0).
__global__ __launch_bounds__(512) void suf_kernel(const bf16* __restrict__ Vt,
                                                  float* __restrict__ SUF) {
  int bh = blockIdx.x;
  int e = threadIdx.x & 63;
  int seg = threadIdx.x >> 6;  // 0..7
  __shared__ float segtot[8][64];
  const bf16* vrow = Vt + ((size_t)bh * 64 + e) * S_LEN;
  float loc[16];
  float carry = 0.f;
#pragma unroll
  for (int j = 15; j >= 0; --j) {
    int jj = seg * 16 + j;
    bf16x8 a = *(const bf16x8*)(vrow + jj * 16);
    bf16x8 b2 = *(const bf16x8*)(vrow + jj * 16 + 8);
    float s = 0.f;
#pragma unroll
    for (int k = 0; k < 8; ++k) s += (float)a[k] + (float)b2[k];
    carry += s;
    loc[j] = carry;
  }
  segtot[seg][e] = carry;
  __syncthreads();
  float add = 0.f;
  for (int s2 = seg + 1; s2 < 8; ++s2) add += segtot[s2][e];
  float* srow = SUF + (size_t)bh * 129 * 64 + e;
#pragma unroll
  for (int j = 0; j < 16; ++j) srow[(size_t)(seg * 16 + j) * 64] = loc[j] + add;
  if (threadIdx.x < 64) srow[(size_t)128 * 64] = 0.f;
}

// softmax+pack one 32-t subtile: 16 S values -> 8 bf16x2 words (pre-swap), lsum.
__device__ __forceinline__ void softmax_pack(const f32x16& sf, bool diag, int lh,
                                             int ls, float& lsum, u32* w8) {
#pragma unroll
  for (int i = 0; i < 8; ++i) {
    float x0 = sf[2 * i], x1 = sf[2 * i + 1];
    if (diag) {
      int t0 = ((2 * i) & 3) + 8 * (i >> 1) + 4 * lh;
      x0 = (t0 <= ls) ? x0 : 0.f;
      x1 = (t0 + 1 <= ls) ? x1 : 0.f;
    }
    float e0 = exp2f(x0), e1 = exp2f(x1);
    lsum += e0 + e1;
    bf16x2 pk;
    pk[0] = (bf16)e0; pk[1] = (bf16)e1;
    w8[i] = __builtin_bit_cast(u32, pk);
  }
}

// Flash attention v6: 1024 blocks x 256 thr (4 waves). Block = 2 q-tiles
// {63-j (big), j (small)} x 2 sweep-halves. Wave w: tile slot = w>>1, half = w&1.
// No LDS / no barriers in the sweep; K/V fragments global->VGPR (L1/L2-hot).
// XCD-clustered mapping: 4 bh per XCD (2 MB K+V working set per L2).
__global__ __launch_bounds__(256, 3) void flash_attn(
    const bf16* __restrict__ Qb, const bf16* __restrict__ Kb,
    const bf16* __restrict__ Vt, const float* __restrict__ SUF,
    bf16* __restrict__ attO) {
  int n = blockIdx.x;            // 0..1023
  int g = n & 7, m = n >> 3;     // XCD id, index within XCD group
  int bh = 4 * g + (m >> 5);     // 4 bh per XCD
  int j = m & 31;                // 0..31
  int b = bh >> 3, h = bh & 7;

  int tid = threadIdx.x;
  int w = tid >> 6, l = tid & 63, lh = l >> 5, ls = l & 31;
  int slot = w >> 1, h2 = w & 1;

  int qt32 = slot ? j : (63 - j);
  int qb_w = qt32 * 32;
  int tmax_w = qb_w + 32;
  int ntw = (tmax_w + 63) >> 6;
  int mid = ntw >> 1;
  int i0 = h2 ? mid : 0;
  int i1 = h2 ? ntw : mid;
  int dsub = (qb_w >> 5) & 1;    // which 32-subtile of last iter is diagonal

  __shared__ float comb[2][64][34];
  __shared__ float lsumS[2][32];

  // Q in registers (B-operand frags): lane ls = q-row, e-slice ki*16 + lh*8
  const bf16* qrow = Qb + ((size_t)(b * S_LEN) + qb_w + ls) * DMODEL + h * 64 + lh * 8;
  bf16x8 qf[4];
#pragma unroll
  for (int ki = 0; ki < 4; ++ki) qf[ki] = *(const bf16x8*)(qrow + ki * 16);

  const bf16* Kg = Kb + ((size_t)(b * S_LEN)) * DMODEL + h * 64;
  const bf16* Vg = Vt + ((size_t)bh * 64) * S_LEN;

  f32x16 acc0 = {}, acc1 = {};
  float lsum = 0.f;

  for (int it = i0; it < i1; ++it) {
    int t0 = it << 6;
    bool last = (it == ntw - 1);          // reachable only by h2==1
    int nsub = (last && dsub == 0) ? 1 : 2;

    // QK^T: S^T[t][s]; A = K rows (lane = t), B = Q (lane = s)
    f32x16 sf0 = {}, sf1 = {};
#pragma unroll
    for (int ki = 0; ki < 4; ++ki) {
      bf16x8 ka = *(const bf16x8*)(Kg + (size_t)(t0 + ls) * DMODEL + (2 * ki + lh) * 8);
      sf0 = __builtin_amdgcn_mfma_f32_32x32x16_bf16(ka, qf[ki], sf0, 0, 0, 0);
    }
    if (nsub == 2) {
#pragma unroll
      for (int ki = 0; ki < 4; ++ki) {
        bf16x8 ka = *(const bf16x8*)(Kg + (size_t)(t0 + 32 + ls) * DMODEL + (2 * ki + lh) * 8);
        sf1 = __builtin_amdgcn_mfma_f32_32x32x16_bf16(ka, qf[ki], sf1, 0, 0, 0);
      }
    }

    // flat softmax + pack to bf16 A-frags (p = exp2(x))
    u32 pw[16];
    softmax_pack(sf0, last && (dsub == 0), lh, ls, lsum, pw);
    PSWAP(pw[0], pw[2]); PSWAP(pw[1], pw[3]);
    PSWAP(pw[4], pw[6]); PSWAP(pw[5], pw[7]);
    if (nsub == 2) {
      softmax_pack(sf1, last && (dsub == 1), lh, ls, lsum, pw + 8);
      PSWAP(pw[8], pw[10]); PSWAP(pw[9], pw[11]);
      PSWAP(pw[12], pw[14]); PSWAP(pw[13], pw[15]);
    }

    // PV: acc[s][e] += P[s][t] V[t][e]; B = V^T rows (lane = e)
#pragma unroll
    for (int u = 0; u < 2; ++u) {
      u32x4 fv = {pw[4 * u], pw[4 * u + 1], pw[4 * u + 2], pw[4 * u + 3]};
      bf16x8 pa = __builtin_bit_cast(bf16x8, fv);
      const bf16* vb = Vg + t0 + (2 * u + lh) * 8;
      bf16x8 vlo = *(const bf16x8*)(vb + (size_t)ls * S_LEN);
      bf16x8 vhi = *(const bf16x8*)(vb + (size_t)(ls + 32) * S_LEN);
      acc0 = __builtin_amdgcn_mfma_f32_32x32x16_bf16(pa, vlo, acc0, 0, 0, 0);
      acc1 = __builtin_amdgcn_mfma_f32_32x32x16_bf16(pa, vhi, acc1, 0, 0, 0);
    }
    if (nsub == 2) {
#pragma unroll
      for (int u = 2; u < 4; ++u) {
        u32x4 fv = {pw[4 * u], pw[4 * u + 1], pw[4 * u + 2], pw[4 * u + 3]};
        bf16x8 pa = __builtin_bit_cast(bf16x8, fv);
        const bf16* vb = Vg + t0 + (2 * u + lh) * 8;
        bf16x8 vlo = *(const bf16x8*)(vb + (size_t)ls * S_LEN);
        bf16x8 vhi = *(const bf16x8*)(vb + (size_t)(ls + 32) * S_LEN);
        acc0 = __builtin_amdgcn_mfma_f32_32x32x16_bf16(pa, vlo, acc0, 0, 0, 0);
        acc1 = __builtin_amdgcn_mfma_f32_32x32x16_bf16(pa, vhi, acc1, 0, 0, 0);
      }
    }
  }

  // combine the two sweep-halves (flat softmax: partials just add)
  if (h2 == 1) {
#pragma unroll
    for (int r = 0; r < 16; ++r) {
      comb[slot][l][r] = acc0[r];
      comb[slot][l][16 + r] = acc1[r];
    }
    comb[slot][l][32] = lsum;
  }
  __syncthreads();
  if (h2 == 0) {
#pragma unroll
    for (int r = 0; r < 16; ++r) {
      acc0[r] += comb[slot][l][r];
      acc1[r] += comb[slot][l][16 + r];
    }
    lsum += comb[slot][l][32];
    lsum += __shfl_xor(lsum, 32, 64);
    lsumS[slot][ls] = lsum;

    int j16 = tmax_w >> 4;
    const float* suf = SUF + ((size_t)bh * 129 + j16) * 64;
    float cnt = (float)(S_LEN - tmax_w);
    float suf0 = suf[ls], suf1 = suf[ls + 32];

    bf16* obase = attO + ((size_t)(b * S_LEN) + qb_w) * DMODEL + h * 64 + ls;
#pragma unroll
    for (int r = 0; r < 16; ++r) {
      int sr = (r & 3) + 8 * (r >> 2) + 4 * lh;
      float inv = 1.f / (lsumS[slot][sr] + cnt);
      obase[(size_t)sr * DMODEL] = (bf16)((acc0[r] + suf0) * inv);
      obase[(size_t)sr * DMODEL + 32] = (bf16)((acc1[r] + suf1) * inv);
    }
  }
}

__global__ __launch_bounds__(256) void ln_kernel(const bf16* __restrict__ x,
                                                 const float* __restrict__ gamma,
                                                 const float* __restrict__ beta,
                                                 float* __restrict__ out) {
  int row = blockIdx.x * 4 + (threadIdx.x >> 6);
  int l = threadIdx.x & 63;
  bf16x8 xv = *(const bf16x8*)(x + (size_t)row * DMODEL + l * 8);
  float xf[8];
  float s = 0.f, s2 = 0.f;
#pragma unroll
  for (int k = 0; k < 8; ++k) {
    xf[k] = (float)xv[k];
    s += xf[k];
    s2 += xf[k] * xf[k];
  }
#pragma unroll
  for (int d = 1; d < 64; d <<= 1) {
    s += __shfl_xor(s, d, 64);
    s2 += __shfl_xor(s2, d, 64);
  }
  float mean = s * (1.f / 512.f);
  float var = s2 * (1.f / 512.f) - mean * mean;
  float rstd = rsqrtf(var + 1e-5f);
  const float4* g4 = reinterpret_cast<const float4*>(gamma) + l * 2;
  const float4* b4 = reinterpret_cast<const float4*>(beta) + l * 2;
  float4 g0 = g4[0], g1 = g4[1], bb0 = b4[0], bb1 = b4[1];
  float4 o0, o1;
  o0.x = (xf[0] - mean) * rstd * g0.x + bb0.x;
  o0.y = (xf[1] - mean) * rstd * g0.y + bb0.y;
  o0.z = (xf[2] - mean) * rstd * g0.z + bb0.z;
  o0.w = (xf[3] - mean) * rstd * g0.w + bb0.w;
  o1.x = (xf[4] - mean) * rstd * g1.x + bb1.x;
  o1.y = (xf[5] - mean) * rstd * g1.y + bb1.y;
  o1.z = (xf[6] - mean) * rstd * g1.z + bb1.z;
  o1.w = (xf[7] - mean) * rstd * g1.w + bb1.w;
  float4* orow = reinterpret_cast<float4*>(out + (size_t)row * DMODEL) + l * 2;
  orow[0] = o0;
  orow[1] = o1;
}

extern "C" void kernel_launch(void* const* d_in, const int* in_sizes, int n_in,
                              void* d_out, int out_size, void* d_ws, size_t ws_size,
                              hipStream_t stream) {
  const float* embed = (const float*)d_in[0];
  const float* Wq = (const float*)d_in[1];
  const float* bq = (const float*)d_in[2];
  const float* Wk = (const float*)d_in[3];
  const float* bk = (const float*)d_in[4];
  const float* Wv = (const float*)d_in[5];
  const float* bv = (const float*)d_in[6];
  const float* Wo = (const float*)d_in[7];
  const float* bo = (const float*)d_in[8];
  const float* gamma = (const float*)d_in[9];
  const float* beta = (const float*)d_in[10];
  float* out = (float*)d_out;

  char* ws = (char*)d_ws;
  size_t off = 0;
  auto alc = [&](size_t b) { size_t o = off; off += (b + 255) & ~(size_t)255; return o; };
  bf16* Eb    = (bf16*)(ws + alc(8192ull * 512 * 2));
  bf16* Wqkv  = (bf16*)(ws + alc(1536ull * 512 * 2));
  bf16* Wob   = (bf16*)(ws + alc(512ull * 512 * 2));
  bf16* Qb    = (bf16*)(ws + alc(8192ull * 512 * 2));
  bf16* Kb    = (bf16*)(ws + alc(8192ull * 512 * 2));
  bf16* Vt    = (bf16*)(ws + alc(8192ull * 512 * 2));
  float* SUF  = (float*)(ws + alc(32ull * 129 * 64 * 4));
  bf16* AttO  = (bf16*)(ws + alc(8192ull * 512 * 2));
  bf16* Xb    = (bf16*)(ws + alc(8192ull * 512 * 2));
  (void)ws_size; (void)n_in; (void)in_sizes; (void)out_size;

  cast_all<<<5120, 256, 0, stream>>>(embed, Wq, Wk, Wv, Wo, Eb, Wqkv, Wob);

  gemm_qkv<<<dim3(64, 12), 256, 0, stream>>>(Eb, Wqkv, bq, bk, bv, Qb, Kb, Vt);
  suf_kernel<<<32, 512, 0, stream>>>(Vt, SUF);
  flash_attn<<<1024, 256, 0, stream>>>(Qb, Kb, Vt, SUF, AttO);
  gemm_wo<<<dim3(64, 4), 256, 0, stream>>>(AttO, Wob, bo, embed, Xb);
  ln_kernel<<<2048, 256, 0, stream>>>(Xb, gamma, beta, out);
}

// Round 10
// 116.870 us; speedup vs baseline: 1.1318x; 1.1318x over previous
//
#include <hip/hip_runtime.h>
#include <hip/hip_bf16.h>

// B=4, S=2048, D=512, H=8, DH=64
// m97-structure 128x128 LDS-staged GEMMs (global_load_lds w16 + XOR swizzle).
// flash v7: swapped-operand QK^T (mfma(K,Q) -> S^T), 32x32x16 MFMA, P in-register
// via bf16x2 packs + v_permlane32_swap_b32; flat softmax (tril zeros pin max~0 ->
// p = exp2(x)); LDS-staged K/V with CORRECT swizzle for 32-row b128 reads:
// chunk ^= (row>>2)&7  (bank16 = (row&3)*8 + chunk -> exactly 2 lanes/bank, free).
// Blocks group 4 similar-length tiles {4j..4j+3} (97% slot utilization); biggest-
// first launch; per-bh blocks land on one XCD L2. Masked tail via V suffix sums.

typedef __bf16 bf16;
typedef __bf16 bf16x8 __attribute__((ext_vector_type(8)));
typedef __bf16 bf16x4v __attribute__((ext_vector_type(4)));
typedef __bf16 bf16x2 __attribute__((ext_vector_type(2)));
typedef float f32x4 __attribute__((ext_vector_type(4)));
typedef float f32x16 __attribute__((ext_vector_type(16)));
typedef unsigned int u32;
typedef u32 u32x4 __attribute__((ext_vector_type(4)));

#define S_LEN 2048
#define DMODEL 512
// log2(e)/sqrt(512): Q pre-scale so softmax exp is a bare exp2
#define QSCALE 0.06375870914f

#define GLDS(g, l) __builtin_amdgcn_global_load_lds(                  \
    (const __attribute__((address_space(1))) void*)(g),               \
    (__attribute__((address_space(3))) void*)(l), 16, 0, 0)

#define PSWAP(a, b) asm volatile("v_permlane32_swap_b32 %0, %1" : "+v"(a), "+v"(b))

// One launch: embed (1,048,576 f4) then Wq,Wk,Wv,Wo (65,536 f4 each).
__global__ __launch_bounds__(256) void cast_all(
    const float* __restrict__ embed, const float* __restrict__ Wq,
    const float* __restrict__ Wk, const float* __restrict__ Wv,
    const float* __restrict__ Wo,
    bf16* __restrict__ Eb, bf16* __restrict__ Wqkv, bf16* __restrict__ Wob) {
  int i = blockIdx.x * 256 + threadIdx.x;
  const float* src;
  bf16* dst;
  int il;
  if (i < 1048576) {
    src = embed; dst = Eb; il = i;
  } else {
    int j = i - 1048576;
    int w = j >> 16;
    il = j & 65535;
    src = (w == 0) ? Wq : (w == 1) ? Wk : (w == 2) ? Wv : Wo;
    dst = (w == 3) ? Wob : Wqkv + (size_t)w * 262144;
  }
  float4 v = reinterpret_cast<const float4*>(src)[il];
  bf16x4v o;
  o[0] = (bf16)v.x; o[1] = (bf16)v.y; o[2] = (bf16)v.z; o[3] = (bf16)v.w;
  *reinterpret_cast<bf16x4v*>(dst + (size_t)il * 4) = o;
}

// ---- 128x128 tile GEMM core: C = A[M,512] * Bw[N,512]^T, K=512, BK=64 ----
__device__ __forceinline__ void gemm128_core(
    const bf16* __restrict__ A, const bf16* __restrict__ Bw,
    int row0, int col0, bf16* As, bf16* Bs, f32x4 (&acc)[4][4]) {
  int tid = threadIdx.x;
  int w = tid >> 6, l = tid & 63, lr = l & 15, lg = l >> 4;
  int wr = w >> 1, wc = w & 1;

  int srow = w * 8 + (l >> 3);
  int scol = ((l & 7) ^ (srow & 7)) << 3;
  const bf16* ga = A + (size_t)(row0 + srow) * DMODEL + scol;
  const bf16* gb = Bw + (size_t)(col0 + srow) * DMODEL + scol;
  char* asb = (char*)As;
  char* bsb = (char*)Bs;
  int sbase = w * 1024;

  int aoff[4], boff[4];
#pragma unroll
  for (int m = 0; m < 4; ++m) {
    aoff[m] = (wr * 64 + m * 16 + lr) * 128 + (((lg ^ (lr & 7))) << 4);
    boff[m] = (wc * 64 + m * 16 + lr) * 128 + (((lg ^ (lr & 7))) << 4);
  }

  for (int k0 = 0; k0 < DMODEL; k0 += 64) {
#pragma unroll
    for (int qt = 0; qt < 4; ++qt) {
      GLDS(ga + (size_t)qt * 32 * DMODEL, asb + qt * 4096 + sbase);
      GLDS(gb + (size_t)qt * 32 * DMODEL, bsb + qt * 4096 + sbase);
    }
    ga += 64; gb += 64;
    __syncthreads();

    bf16x8 af[2][4], bfv[2][4];
#pragma unroll
    for (int m = 0; m < 4; ++m) {
      af[0][m] = *(const bf16x8*)(asb + aoff[m]);
      af[1][m] = *(const bf16x8*)(asb + (aoff[m] ^ 0x40));
      bfv[0][m] = *(const bf16x8*)(bsb + boff[m]);
      bfv[1][m] = *(const bf16x8*)(bsb + (boff[m] ^ 0x40));
    }
#pragma unroll
    for (int m = 0; m < 4; ++m)
#pragma unroll
      for (int n = 0; n < 4; ++n) {
        acc[m][n] = __builtin_amdgcn_mfma_f32_16x16x32_bf16(af[0][m], bfv[0][n], acc[m][n], 0, 0, 0);
        acc[m][n] = __builtin_amdgcn_mfma_f32_16x16x32_bf16(af[1][m], bfv[1][n], acc[m][n], 0, 0, 0);
      }
    __syncthreads();
  }
}

// Fused QKV GEMM: Wqkv[1536][512]; col-tiles 0-3 = Q, 4-7 = K, 8-11 = V.
__global__ __launch_bounds__(256) void gemm_qkv(
    const bf16* __restrict__ A, const bf16* __restrict__ Wqkv,
    const float* __restrict__ bq, const float* __restrict__ bk, const float* __restrict__ bv,
    bf16* __restrict__ Qb, bf16* __restrict__ Kb, bf16* __restrict__ Vt) {
  __shared__ __align__(16) bf16 As[128 * 64];
  __shared__ __align__(16) bf16 Bs[128 * 64];
  int row0 = blockIdx.x * 128, col0 = blockIdx.y * 128;
  f32x4 acc[4][4] = {};
  gemm128_core(A, Wqkv, row0, col0, As, Bs, acc);

  int tid = threadIdx.x;
  int w = tid >> 6, l = tid & 63, lr = l & 15, lg = l >> 4;
  int wr = w >> 1, wc = w & 1;
  int z2 = col0 >> 9;  // 0=Q 1=K 2=V (uniform per block)
  if (z2 < 2) {
    bf16* O = z2 ? Kb : Qb;
    const float* bias = z2 ? bk : bq;
    float qs = z2 ? 1.0f : QSCALE;
#pragma unroll
    for (int n = 0; n < 4; ++n) {
      int cg = (col0 & 511) + wc * 64 + n * 16 + lr;
      float bi = bias[cg];
#pragma unroll
      for (int m = 0; m < 4; ++m) {
        int rg = row0 + wr * 64 + m * 16 + lg * 4;
#pragma unroll
        for (int r = 0; r < 4; ++r)
          O[(size_t)(rg + r) * DMODEL + cg] = (bf16)((acc[m][n][r] + bi) * qs);
      }
    }
  } else {
    // V: store transposed Vt[b][h][e][s]
#pragma unroll
    for (int n = 0; n < 4; ++n) {
      int ep = (col0 & 511) + wc * 64 + n * 16 + lr;
      int h = ep >> 6, e = ep & 63;
      float bi = bv[ep];
#pragma unroll
      for (int m = 0; m < 4; ++m) {
        int rg = row0 + wr * 64 + m * 16 + lg * 4;
        int b = rg >> 11, s0 = rg & 2047;
        bf16x4v pk;
#pragma unroll
        for (int r = 0; r < 4; ++r) pk[r] = (bf16)(acc[m][n][r] + bi);
        *(bf16x4v*)(Vt + ((size_t)((b * 8 + h) * 64 + e)) * S_LEN + s0) = pk;
      }
    }
  }
}

// Wo GEMM + bias + residual, bf16 out (LN reads bf16).
__global__ __launch_bounds__(256) void gemm_wo(
    const bf16* __restrict__ A, const bf16* __restrict__ W,
    const float* __restrict__ bo, const float* __restrict__ embed,
    bf16* __restrict__ X) {
  __shared__ __align__(16) bf16 As[128 * 64];
  __shared__ __align__(16) bf16 Bs[128 * 64];
  int row0 = blockIdx.x * 128, col0 = blockIdx.y * 128;
  f32x4 acc[4][4] = {};
  gemm128_core(A, W, row0, col0, As, Bs, acc);

  int tid = threadIdx.x;
  int w = tid >> 6, l = tid & 63, lr = l & 15, lg = l >> 4;
  int wr = w >> 1, wc = w & 1;
#pragma unroll
  for (int n = 0; n < 4; ++n) {
    int cg = col0 + wc * 64 + n * 16 + lr;
    float bi = bo[cg];
#pragma unroll
    for (int m = 0; m < 4; ++m) {
      int rg = row0 + wr * 64 + m * 16 + lg * 4;
#pragma unroll
      for (int r = 0; r < 4; ++r)
        X[(size_t)(rg + r) * DMODEL + cg] =
            (bf16)(acc[m][n][r] + bi + embed[(size_t)(rg + r) * DMODEL + cg]);
    }
  }
}

// SUF[bh][j][e] = sum_{t >= 16j} V[t][e], j = 0..128 (SUF[128]=0).
__global__ __launch_bounds__(512) void suf_kernel(const bf16* __restrict__ Vt,
                                                  float* __restrict__ SUF) {
  int bh = blockIdx.x;
  int e = threadIdx.x & 63;
  int seg = threadIdx.x >> 6;  // 0..7
  __shared__ float segtot[8][64];
  const bf16* vrow = Vt + ((size_t)bh * 64 + e) * S_LEN;
  float loc[16];
  float carry = 0.f;
#pragma unroll
  for (int j = 15; j >= 0; --j) {
    int jj = seg * 16 + j;
    bf16x8 a = *(const bf16x8*)(vrow + jj * 16);
    bf16x8 b2 = *(const bf16x8*)(vrow + jj * 16 + 8);
    float s = 0.f;
#pragma unroll
    for (int k = 0; k < 8; ++k) s += (float)a[k] + (float)b2[k];
    carry += s;
    loc[j] = carry;
  }
  segtot[seg][e] = carry;
  __syncthreads();
  float add = 0.f;
  for (int s2 = seg + 1; s2 < 8; ++s2) add += segtot[s2][e];
  float* srow = SUF + (size_t)bh * 129 * 64 + e;
#pragma unroll
  for (int j = 0; j < 16; ++j) srow[(size_t)(seg * 16 + j) * 64] = loc[j] + add;
  if (threadIdx.x < 64) srow[(size_t)128 * 64] = 0.f;
}

// softmax+pack one 32-t subtile: 16 S values -> 8 bf16x2 words (pre-swap), lsum.
__device__ __forceinline__ void softmax_pack(const f32x16& sf, bool diag, int lh,
                                             int ls, float& lsum, u32* w8) {
#pragma unroll
  for (int i = 0; i < 8; ++i) {
    float x0 = sf[2 * i], x1 = sf[2 * i + 1];
    if (diag) {
      int t0 = ((2 * i) & 3) + 8 * (i >> 1) + 4 * lh;
      x0 = (t0 <= ls) ? x0 : 0.f;
      x1 = (t0 + 1 <= ls) ? x1 : 0.f;
    }
    float e0 = exp2f(x0), e1 = exp2f(x1);
    lsum += e0 + e1;
    bf16x2 pk;
    pk[0] = (bf16)e0; pk[1] = (bf16)e1;
    w8[i] = __builtin_bit_cast(u32, pk);
  }
}

// Flash attention v7: 512 blocks x 256 thr (4 waves). Block (bh, j) owns q-tiles
// {4j..4j+3} (wave ws -> tile 4j+ws), shared KV sweep nt = 2j+2. LDS-staged K/V,
// double-buffered GLDS, swizzle chunk^=(row>>2)&7 on both sides.
__global__ __launch_bounds__(256, 4) void flash_attn(
    const bf16* __restrict__ Qb, const bf16* __restrict__ Kb,
    const bf16* __restrict__ Vt, const float* __restrict__ SUF,
    bf16* __restrict__ attO) {
  int bx = blockIdx.x;
  int bh = bx & 31;
  int j = 15 - (bx >> 5);        // biggest-first
  int b = bh >> 3, h = bh & 7;

  int tid = threadIdx.x;
  int w = tid >> 6, l = tid & 63, lh = l >> 5, ls = l & 31;

  int qt32 = 4 * j + w;
  int qb_w = qt32 * 32;
  int tmax_w = qb_w + 32;
  int ntw = (tmax_w + 63) >> 6;   // this wave's compute iters
  int nt = 2 * j + 2;             // block-uniform sweep length (= max ntw)
  int dsub = qt32 & 1;            // which 32-subtile of last iter is diagonal

  __shared__ __align__(16) bf16 kl[2][64 * 64];  // K tile [t][e], swizzled
  __shared__ __align__(16) bf16 vl[2][64 * 64];  // V^T tile [e][t], swizzled
  __shared__ float lsumS[4][32];

  // Q in registers (B-operand frags): lane ls = q-row, e-slice ki*16 + lh*8
  const bf16* qrow = Qb + ((size_t)(b * S_LEN) + qb_w + ls) * DMODEL + h * 64 + lh * 8;
  bf16x8 qf[4];
#pragma unroll
  for (int ki = 0; ki < 4; ++ki) qf[ki] = *(const bf16x8*)(qrow + ki * 16);

  f32x16 acc0 = {}, acc1 = {};  // PV out: e 0..31 / e 32..63
  float lsum = 0.f;

  // staging: 256 thr, 2 issues per buffer: issue q covers rows q*32+(tid>>3),
  // chunk tid&7; source pre-swizzled chunk ^= (row>>2)&7; dest linear.
  int grow = tid >> 3, gch = tid & 7;
  int sch0 = (gch ^ ((grow >> 2) & 7)) << 3;          // rows 0..31
  int sch1 = (gch ^ (((grow + 32) >> 2) & 7)) << 3;   // rows 32..63
  const bf16* Kg0 = Kb + ((size_t)(b * S_LEN) + grow) * DMODEL + h * 64 + sch0;
  const bf16* Kg1 = Kb + ((size_t)(b * S_LEN) + grow + 32) * DMODEL + h * 64 + sch1;
  const bf16* Vg0 = Vt + ((size_t)(bh * 64) + grow) * S_LEN + sch0;
  const bf16* Vg1 = Vt + ((size_t)(bh * 64) + grow + 32) * S_LEN + sch1;
  int sdst = w * 1024;  // wave-uniform LDS dest base (lane*16 implicit)

  // fragment-read swizzled chunk offsets: chunk c = 2*ki+lh, row-swz = ls>>2
  int cx[4];
#pragma unroll
  for (int ki = 0; ki < 4; ++ki) cx[ki] = (((2 * ki + lh) ^ (ls >> 2)) << 4);
  int rb = ls * 128;

  // prologue: stage tile 0 into buf 0
  GLDS(Kg0, (char*)kl[0] + sdst);
  GLDS(Kg1, (char*)kl[0] + 4096 + sdst);
  GLDS(Vg0, (char*)vl[0] + sdst);
  GLDS(Vg1, (char*)vl[0] + 4096 + sdst);
  asm volatile("s_waitcnt vmcnt(0)" ::: "memory");
  __syncthreads();

  int cur = 0;
  for (int it = 0; it < nt; ++it) {
    if (it + 1 < nt) {
      int t1 = (it + 1) << 6;
      GLDS(Kg0 + (size_t)t1 * DMODEL, (char*)kl[cur ^ 1] + sdst);
      GLDS(Kg1 + (size_t)t1 * DMODEL, (char*)kl[cur ^ 1] + 4096 + sdst);
      GLDS(Vg0 + t1, (char*)vl[cur ^ 1] + sdst);
      GLDS(Vg1 + t1, (char*)vl[cur ^ 1] + 4096 + sdst);
    }
    if (it < ntw) {
      char* klb = (char*)kl[cur];
      char* vlb = (char*)vl[cur];
      bool last = (it == ntw - 1);
      int nsub = (last && dsub == 0) ? 1 : 2;

      // QK^T: S^T[t][s]; A = K rows (lane = t), B = Q (lane = s)
      f32x16 sf0 = {}, sf1 = {};
#pragma unroll
      for (int ki = 0; ki < 4; ++ki) {
        bf16x8 ka = *(const bf16x8*)(klb + rb + cx[ki]);
        sf0 = __builtin_amdgcn_mfma_f32_32x32x16_bf16(ka, qf[ki], sf0, 0, 0, 0);
      }
      if (nsub == 2) {
#pragma unroll
        for (int ki = 0; ki < 4; ++ki) {
          bf16x8 ka = *(const bf16x8*)(klb + rb + 32 * 128 + cx[ki]);
          sf1 = __builtin_amdgcn_mfma_f32_32x32x16_bf16(ka, qf[ki], sf1, 0, 0, 0);
        }
      }

      // flat softmax + pack to bf16 A-frags (p = exp2(x))
      u32 pw[16];
      softmax_pack(sf0, last && (dsub == 0), lh, ls, lsum, pw);
      PSWAP(pw[0], pw[2]); PSWAP(pw[1], pw[3]);
      PSWAP(pw[4], pw[6]); PSWAP(pw[5], pw[7]);
      if (nsub == 2) {
        softmax_pack(sf1, last && (dsub == 1), lh, ls, lsum, pw + 8);
        PSWAP(pw[8], pw[10]); PSWAP(pw[9], pw[11]);
        PSWAP(pw[12], pw[14]); PSWAP(pw[13], pw[15]);
      }

      // PV: acc[s][e] += P[s][t] V[t][e]; B = V^T rows (lane = e)
#pragma unroll
      for (int u = 0; u < 2; ++u) {
        u32x4 fv = {pw[4 * u], pw[4 * u + 1], pw[4 * u + 2], pw[4 * u + 3]};
        bf16x8 pa = __builtin_bit_cast(bf16x8, fv);
        bf16x8 vlo = *(const bf16x8*)(vlb + rb + cx[u]);
        bf16x8 vhi = *(const bf16x8*)(vlb + rb + 32 * 128 + cx[u]);
        acc0 = __builtin_amdgcn_mfma_f32_32x32x16_bf16(pa, vlo, acc0, 0, 0, 0);
        acc1 = __builtin_amdgcn_mfma_f32_32x32x16_bf16(pa, vhi, acc1, 0, 0, 0);
      }
      if (nsub == 2) {
#pragma unroll
        for (int u = 2; u < 4; ++u) {
          u32x4 fv = {pw[4 * u], pw[4 * u + 1], pw[4 * u + 2], pw[4 * u + 3]};
          bf16x8 pa = __builtin_bit_cast(bf16x8, fv);
          bf16x8 vlo = *(const bf16x8*)(vlb + rb + cx[u]);
          bf16x8 vhi = *(const bf16x8*)(vlb + rb + 32 * 128 + cx[u]);
          acc0 = __builtin_amdgcn_mfma_f32_32x32x16_bf16(pa, vlo, acc0, 0, 0, 0);
          acc1 = __builtin_amdgcn_mfma_f32_32x32x16_bf16(pa, vhi, acc1, 0, 0, 0);
        }
      }
    }
    asm volatile("s_waitcnt vmcnt(0)" ::: "memory");
    __syncthreads();
    cur ^= 1;
  }

  // combine lane halves: lsum_total[s] = lsum(lane s) + lsum(lane s+32)
  lsum += __shfl_xor(lsum, 32, 64);
  lsumS[w][ls] = lsum;

  int j16 = tmax_w >> 4;
  const float* suf = SUF + ((size_t)bh * 129 + j16) * 64;
  float cnt = (float)(S_LEN - tmax_w);
  float suf0 = suf[ls], suf1 = suf[ls + 32];

  bf16* obase = attO + ((size_t)(b * S_LEN) + qb_w) * DMODEL + h * 64 + ls;
#pragma unroll
  for (int r = 0; r < 16; ++r) {
    int sr = (r & 3) + 8 * (r >> 2) + 4 * lh;
    float inv = 1.f / (lsumS[w][sr] + cnt);
    obase[(size_t)sr * DMODEL] = (bf16)((acc0[r] + suf0) * inv);
    obase[(size_t)sr * DMODEL + 32] = (bf16)((acc1[r] + suf1) * inv);
  }
}

__global__ __launch_bounds__(256) void ln_kernel(const bf16* __restrict__ x,
                                                 const float* __restrict__ gamma,
                                                 const float* __restrict__ beta,
                                                 float* __restrict__ out) {
  int row = blockIdx.x * 4 + (threadIdx.x >> 6);
  int l = threadIdx.x & 63;
  bf16x8 xv = *(const bf16x8*)(x + (size_t)row * DMODEL + l * 8);
  float xf[8];
  float s = 0.f, s2 = 0.f;
#pragma unroll
  for (int k = 0; k < 8; ++k) {
    xf[k] = (float)xv[k];
    s += xf[k];
    s2 += xf[k] * xf[k];
  }
#pragma unroll
  for (int d = 1; d < 64; d <<= 1) {
    s += __shfl_xor(s, d, 64);
    s2 += __shfl_xor(s2, d, 64);
  }
  float mean = s * (1.f / 512.f);
  float var = s2 * (1.f / 512.f) - mean * mean;
  float rstd = rsqrtf(var + 1e-5f);
  const float4* g4 = reinterpret_cast<const float4*>(gamma) + l * 2;
  const float4* b4 = reinterpret_cast<const float4*>(beta) + l * 2;
  float4 g0 = g4[0], g1 = g4[1], bb0 = b4[0], bb1 = b4[1];
  float4 o0, o1;
  o0.x = (xf[0] - mean) * rstd * g0.x + bb0.x;
  o0.y = (xf[1] - mean) * rstd * g0.y + bb0.y;
  o0.z = (xf[2] - mean) * rstd * g0.z + bb0.z;
  o0.w = (xf[3] - mean) * rstd * g0.w + bb0.w;
  o1.x = (xf[4] - mean) * rstd * g1.x + bb1.x;
  o1.y = (xf[5] - mean) * rstd * g1.y + bb1.y;
  o1.z = (xf[6] - mean) * rstd * g1.z + bb1.z;
  o1.w = (xf[7] - mean) * rstd * g1.w + bb1.w;
  float4* orow = reinterpret_cast<float4*>(out + (size_t)row * DMODEL) + l * 2;
  orow[0] = o0;
  orow[1] = o1;
}

extern "C" void kernel_launch(void* const* d_in, const int* in_sizes, int n_in,
                              void* d_out, int out_size, void* d_ws, size_t ws_size,
                              hipStream_t stream) {
  const float* embed = (const float*)d_in[0];
  const float* Wq = (const float*)d_in[1];
  const float* bq = (const float*)d_in[2];
  const float* Wk = (const float*)d_in[3];
  const float* bk = (const float*)d_in[4];
  const float* Wv = (const float*)d_in[5];
  const float* bv = (const float*)d_in[6];
  const float* Wo = (const float*)d_in[7];
  const float* bo = (const float*)d_in[8];
  const float* gamma = (const float*)d_in[9];
  const float* beta = (const float*)d_in[10];
  float* out = (float*)d_out;

  char* ws = (char*)d_ws;
  size_t off = 0;
  auto alc = [&](size_t b) { size_t o = off; off += (b + 255) & ~(size_t)255; return o; };
  bf16* Eb    = (bf16*)(ws + alc(8192ull * 512 * 2));
  bf16* Wqkv  = (bf16*)(ws + alc(1536ull * 512 * 2));
  bf16* Wob   = (bf16*)(ws + alc(512ull * 512 * 2));
  bf16* Qb    = (bf16*)(ws + alc(8192ull * 512 * 2));
  bf16* Kb    = (bf16*)(ws + alc(8192ull * 512 * 2));
  bf16* Vt    = (bf16*)(ws + alc(8192ull * 512 * 2));
  float* SUF  = (float*)(ws + alc(32ull * 129 * 64 * 4));
  bf16* AttO  = (bf16*)(ws + alc(8192ull * 512 * 2));
  bf16* Xb    = (bf16*)(ws + alc(8192ull * 512 * 2));
  (void)ws_size; (void)n_in; (void)in_sizes; (void)out_size;

  cast_all<<<5120, 256, 0, stream>>>(embed, Wq, Wk, Wv, Wo, Eb, Wqkv, Wob);

  gemm_qkv<<<dim3(64, 12), 256, 0, stream>>>(Eb, Wqkv, bq, bk, bv, Qb, Kb, Vt);
  suf_kernel<<<32, 512, 0, stream>>>(Vt, SUF);
  flash_attn<<<512, 256, 0, stream>>>(Qb, Kb, Vt, SUF, AttO);
  gemm_wo<<<dim3(64, 4), 256, 0, stream>>>(AttO, Wob, bo, embed, Xb);
  ln_kernel<<<2048, 256, 0, stream>>>(Xb, gamma, beta, out);
}

// Round 11
// 112.495 us; speedup vs baseline: 1.1758x; 1.0389x over previous
//
#include <hip/hip_runtime.h>
#include <hip/hip_bf16.h>

// B=4, S=2048, D=512, H=8, DH=64
// GEMMs: m97-structure 128x128 LDS-staged (GLDS w16 + XOR swizzle); gemm_qkv reads
// f32 embed directly (reg-staged A with inline cast + swizzled ds_write, counted
// vmcnt). flash: round-7 v4 kernel verbatim (53 us measured, 0 conflicts):
// 8 waves = two complementary q-tiles sharing one KV sweep, GLDS dbuf, flat
// softmax via exp2 (tril zeros pin max~0), masked tail via V suffix sums.

typedef __bf16 bf16;
typedef __bf16 bf16x8 __attribute__((ext_vector_type(8)));
typedef __bf16 bf16x4v __attribute__((ext_vector_type(4)));
typedef float f32x4 __attribute__((ext_vector_type(4)));

#define S_LEN 2048
#define DMODEL 512
// log2(e)/sqrt(512): Q pre-scale so softmax exp is a bare exp2
#define QSCALE 0.06375870914f

#define GLDS(g, l) __builtin_amdgcn_global_load_lds(                  \
    (const __attribute__((address_space(1))) void*)(g),               \
    (__attribute__((address_space(3))) void*)(l), 16, 0, 0)

// Weights only: Wq,Wk,Wv -> contiguous Wqkv[1536][512]; Wo -> Wob
__global__ __launch_bounds__(256) void cast_w(
    const float* __restrict__ a0, const float* __restrict__ a1,
    const float* __restrict__ a2, const float* __restrict__ a3,
    bf16* __restrict__ o0, bf16* __restrict__ o1,
    bf16* __restrict__ o2, bf16* __restrict__ o3) {
  int y = blockIdx.y;
  const float* in = (y == 0) ? a0 : (y == 1) ? a1 : (y == 2) ? a2 : a3;
  bf16* out = (y == 0) ? o0 : (y == 1) ? o1 : (y == 2) ? o2 : o3;
  int i = blockIdx.x * 256 + threadIdx.x;
  float4 v = reinterpret_cast<const float4*>(in)[i];
  bf16x4v o;
  o[0] = (bf16)v.x; o[1] = (bf16)v.y; o[2] = (bf16)v.z; o[3] = (bf16)v.w;
  *reinterpret_cast<bf16x4v*>(out + (size_t)i * 4) = o;
}

// Fused QKV GEMM, A = f32 embed (reg-staged + inline cast), B = bf16 Wqkv (GLDS).
// Wqkv[1536][512]; col-tiles 0-3 = Q, 4-7 = K, 8-11 = V.
__global__ __launch_bounds__(256) void gemm_qkv(
    const float* __restrict__ Af32, const bf16* __restrict__ Wqkv,
    const float* __restrict__ bq, const float* __restrict__ bk, const float* __restrict__ bv,
    bf16* __restrict__ Qb, bf16* __restrict__ Kb, bf16* __restrict__ Vt) {
  __shared__ __align__(16) bf16 As[128 * 64];
  __shared__ __align__(16) bf16 Bs[128 * 64];
  int row0 = blockIdx.x * 128, col0 = blockIdx.y * 128;
  int tid = threadIdx.x;
  int w = tid >> 6, l = tid & 63, lr = l & 15, lg = l >> 4;
  int wr = w >> 1, wc = w & 1;

  // B staging (GLDS, pre-swizzled source chunk)
  int srow = w * 8 + (l >> 3);            // 0..31
  int scol = ((l & 7) ^ (srow & 7)) << 3;
  const bf16* gb = Wqkv + (size_t)(col0 + srow) * DMODEL + scol;
  char* asb = (char*)As;
  char* bsb = (char*)Bs;
  int sbase = w * 1024;

  // A: f32 direct + cvt + swizzled ds_write (same bank pattern as reads: free)
  int ac = l & 7;
  const float* ga = Af32 + (size_t)(row0 + srow) * DMODEL + ac * 8;
  int awoff = srow * 128 + ((ac ^ (srow & 7)) << 4);

  int aoff[4], boff[4];
#pragma unroll
  for (int m = 0; m < 4; ++m) {
    aoff[m] = (wr * 64 + m * 16 + lr) * 128 + (((lg ^ (lr & 7))) << 4);
    boff[m] = (wc * 64 + m * 16 + lr) * 128 + (((lg ^ (lr & 7))) << 4);
  }

  f32x4 acc[4][4] = {};
  float4 ar[4][2];
#pragma unroll
  for (int u = 0; u < 4; ++u) {
    ar[u][0] = *(const float4*)(ga + (size_t)u * 32 * DMODEL);
    ar[u][1] = *(const float4*)(ga + (size_t)u * 32 * DMODEL + 4);
  }

  for (int k0 = 0; k0 < DMODEL; k0 += 64) {
#pragma unroll
    for (int qt = 0; qt < 4; ++qt)
      GLDS(gb + (size_t)qt * 32 * DMODEL, bsb + qt * 4096 + sbase);
    gb += 64;

    // cvt + ds_write A (from regs loaded last iter)
#pragma unroll
    for (int u = 0; u < 4; ++u) {
      bf16x8 av;
      av[0] = (bf16)ar[u][0].x; av[1] = (bf16)ar[u][0].y;
      av[2] = (bf16)ar[u][0].z; av[3] = (bf16)ar[u][0].w;
      av[4] = (bf16)ar[u][1].x; av[5] = (bf16)ar[u][1].y;
      av[6] = (bf16)ar[u][1].z; av[7] = (bf16)ar[u][1].w;
      *(bf16x8*)(asb + u * 4096 + awoff) = av;
    }
    ga += 64;
    if (k0 + 64 < DMODEL) {
      // prefetch next A chunk; counted vmcnt leaves these 8 loads in flight
#pragma unroll
      for (int u = 0; u < 4; ++u) {
        ar[u][0] = *(const float4*)(ga + (size_t)u * 32 * DMODEL);
        ar[u][1] = *(const float4*)(ga + (size_t)u * 32 * DMODEL + 4);
      }
      asm volatile("s_waitcnt vmcnt(8)" ::: "memory");
    } else {
      asm volatile("s_waitcnt vmcnt(0)" ::: "memory");
    }
    __syncthreads();

    bf16x8 af[2][4], bfv[2][4];
#pragma unroll
    for (int m = 0; m < 4; ++m) {
      af[0][m] = *(const bf16x8*)(asb + aoff[m]);
      af[1][m] = *(const bf16x8*)(asb + (aoff[m] ^ 0x40));
      bfv[0][m] = *(const bf16x8*)(bsb + boff[m]);
      bfv[1][m] = *(const bf16x8*)(bsb + (boff[m] ^ 0x40));
    }
#pragma unroll
    for (int m = 0; m < 4; ++m)
#pragma unroll
      for (int n = 0; n < 4; ++n) {
        acc[m][n] = __builtin_amdgcn_mfma_f32_16x16x32_bf16(af[0][m], bfv[0][n], acc[m][n], 0, 0, 0);
        acc[m][n] = __builtin_amdgcn_mfma_f32_16x16x32_bf16(af[1][m], bfv[1][n], acc[m][n], 0, 0, 0);
      }
    __syncthreads();
  }

  int z2 = col0 >> 9;  // 0=Q 1=K 2=V (uniform per block)
  if (z2 < 2) {
    bf16* O = z2 ? Kb : Qb;
    const float* bias = z2 ? bk : bq;
    float qs = z2 ? 1.0f : QSCALE;
#pragma unroll
    for (int n = 0; n < 4; ++n) {
      int cg = (col0 & 511) + wc * 64 + n * 16 + lr;
      float bi = bias[cg];
#pragma unroll
      for (int m = 0; m < 4; ++m) {
        int rg = row0 + wr * 64 + m * 16 + lg * 4;
#pragma unroll
        for (int r = 0; r < 4; ++r)
          O[(size_t)(rg + r) * DMODEL + cg] = (bf16)((acc[m][n][r] + bi) * qs);
      }
    }
  } else {
    // V: store transposed Vt[b][h][e][s]
#pragma unroll
    for (int n = 0; n < 4; ++n) {
      int ep = (col0 & 511) + wc * 64 + n * 16 + lr;
      int h = ep >> 6, e = ep & 63;
      float bi = bv[ep];
#pragma unroll
      for (int m = 0; m < 4; ++m) {
        int rg = row0 + wr * 64 + m * 16 + lg * 4;
        int b = rg >> 11, s0 = rg & 2047;
        bf16x4v pk;
#pragma unroll
        for (int r = 0; r < 4; ++r) pk[r] = (bf16)(acc[m][n][r] + bi);
        *(bf16x4v*)(Vt + ((size_t)((b * 8 + h) * 64 + e)) * S_LEN + s0) = pk;
      }
    }
  }
}

// ---- 128x128 tile GEMM core (bf16 A via GLDS) for gemm_wo ----
__device__ __forceinline__ void gemm128_core(
    const bf16* __restrict__ A, const bf16* __restrict__ Bw,
    int row0, int col0, bf16* As, bf16* Bs, f32x4 (&acc)[4][4]) {
  int tid = threadIdx.x;
  int w = tid >> 6, l = tid & 63, lr = l & 15, lg = l >> 4;
  int wr = w >> 1, wc = w & 1;

  int srow = w * 8 + (l >> 3);
  int scol = ((l & 7) ^ (srow & 7)) << 3;
  const bf16* ga = A + (size_t)(row0 + srow) * DMODEL + scol;
  const bf16* gb = Bw + (size_t)(col0 + srow) * DMODEL + scol;
  char* asb = (char*)As;
  char* bsb = (char*)Bs;
  int sbase = w * 1024;

  int aoff[4], boff[4];
#pragma unroll
  for (int m = 0; m < 4; ++m) {
    aoff[m] = (wr * 64 + m * 16 + lr) * 128 + (((lg ^ (lr & 7))) << 4);
    boff[m] = (wc * 64 + m * 16 + lr) * 128 + (((lg ^ (lr & 7))) << 4);
  }

  for (int k0 = 0; k0 < DMODEL; k0 += 64) {
#pragma unroll
    for (int qt = 0; qt < 4; ++qt) {
      GLDS(ga + (size_t)qt * 32 * DMODEL, asb + qt * 4096 + sbase);
      GLDS(gb + (size_t)qt * 32 * DMODEL, bsb + qt * 4096 + sbase);
    }
    ga += 64; gb += 64;
    __syncthreads();

    bf16x8 af[2][4], bfv[2][4];
#pragma unroll
    for (int m = 0; m < 4; ++m) {
      af[0][m] = *(const bf16x8*)(asb + aoff[m]);
      af[1][m] = *(const bf16x8*)(asb + (aoff[m] ^ 0x40));
      bfv[0][m] = *(const bf16x8*)(bsb + boff[m]);
      bfv[1][m] = *(const bf16x8*)(bsb + (boff[m] ^ 0x40));
    }
#pragma unroll
    for (int m = 0; m < 4; ++m)
#pragma unroll
      for (int n = 0; n < 4; ++n) {
        acc[m][n] = __builtin_amdgcn_mfma_f32_16x16x32_bf16(af[0][m], bfv[0][n], acc[m][n], 0, 0, 0);
        acc[m][n] = __builtin_amdgcn_mfma_f32_16x16x32_bf16(af[1][m], bfv[1][n], acc[m][n], 0, 0, 0);
      }
    __syncthreads();
  }
}

// Wo GEMM + bias + residual, bf16 out (LN reads bf16).
__global__ __launch_bounds__(256) void gemm_wo(
    const bf16* __restrict__ A, const bf16* __restrict__ W,
    const float* __restrict__ bo, const float* __restrict__ embed,
    bf16* __restrict__ X) {
  __shared__ __align__(16) bf16 As[128 * 64];
  __shared__ __align__(16) bf16 Bs[128 * 64];
  int row0 = blockIdx.x * 128, col0 = blockIdx.y * 128;
  f32x4 acc[4][4] = {};
  gemm128_core(A, W, row0, col0, As, Bs, acc);

  int tid = threadIdx.x;
  int w = tid >> 6, l = tid & 63, lr = l & 15, lg = l >> 4;
  int wr = w >> 1, wc = w & 1;
#pragma unroll
  for (int n = 0; n < 4; ++n) {
    int cg = col0 + wc * 64 + n * 16 + lr;
    float bi = bo[cg];
#pragma unroll
    for (int m = 0; m < 4; ++m) {
      int rg = row0 + wr * 64 + m * 16 + lg * 4;
#pragma unroll
      for (int r = 0; r < 4; ++r)
        X[(size_t)(rg + r) * DMODEL + cg] =
            (bf16)(acc[m][n][r] + bi + embed[(size_t)(rg + r) * DMODEL + cg]);
    }
  }
}

// SUF[bh][j][e] = sum_{t >= 16j} V[t][e], j = 0..128 (SUF[128]=0).
// 256 blocks: (bh, e-group of 8); 256 thr = (el 0..7, seg 0..31), 4 chunks/seg.
__global__ __launch_bounds__(256) void suf_kernel(const bf16* __restrict__ Vt,
                                                  float* __restrict__ SUF) {
  int bh = blockIdx.x >> 3;
  int eg = blockIdx.x & 7;
  int el = threadIdx.x & 7;
  int seg = threadIdx.x >> 3;  // 0..31
  int e = eg * 8 + el;
  __shared__ float segtot[32][9];
  const bf16* vrow = Vt + ((size_t)bh * 64 + e) * S_LEN;
  float loc[4];
  float carry = 0.f;
#pragma unroll
  for (int j = 3; j >= 0; --j) {
    int jj = seg * 4 + j;
    bf16x8 a = *(const bf16x8*)(vrow + jj * 16);
    bf16x8 b2 = *(const bf16x8*)(vrow + jj * 16 + 8);
    float s = 0.f;
#pragma unroll
    for (int k = 0; k < 8; ++k) s += (float)a[k] + (float)b2[k];
    carry += s;
    loc[j] = carry;
  }
  segtot[seg][el] = carry;
  __syncthreads();
  float add = 0.f;
  for (int s2 = seg + 1; s2 < 32; ++s2) add += segtot[s2][el];
  float* srow = SUF + (size_t)bh * 129 * 64 + e;
#pragma unroll
  for (int j = 0; j < 4; ++j) srow[(size_t)(seg * 4 + j) * 64] = loc[j] + add;
  if (seg == 0) srow[(size_t)128 * 64] = 0.f;
}

// Flash attention (round-7 verbatim, 53 us measured): 8 waves, waves 0-3 = big
// q-tile (16+p), waves 4-7 = small q-tile (15-p), one shared KV sweep (nt=17+p),
// double-buffered GLDS staging, flat softmax via bare exp2, setprio on MFMA.
__global__ __launch_bounds__(512) void flash_attn(
    const bf16* __restrict__ Qb, const bf16* __restrict__ Kb,
    const bf16* __restrict__ Vt, const float* __restrict__ SUF,
    bf16* __restrict__ attO) {
  int bh = blockIdx.y;
  int b = bh >> 3, h = bh & 7;
  int p = (int)gridDim.x - 1 - (int)blockIdx.x;  // 15..0, biggest first
  int tid = threadIdx.x;
  int w = tid >> 6, l = tid & 63, lr = l & 15, lg = l >> 4;
  int wsub = w & 3;
  int qtile = (w < 4) ? (16 + p) : (15 - p);
  int qb = qtile * 64;
  int nt = 17 + p;  // block-uniform KV-tile count (covers big tile's range)

  __shared__ __align__(16) bf16 kl[2][64 * 64];   // K tile [t][e], swizzled
  __shared__ __align__(16) bf16 vl[2][64 * 64];   // V^T tile [e][t], swizzled
  __shared__ __align__(16) bf16 pl[8][16 * 64];   // per-wave P tile [s][t], swizzled

  int srow = qb + 16 * wsub + lr;
  const bf16* qptr = Qb + ((size_t)(b * S_LEN) + srow) * DMODEL + h * 64 + lg * 8;
  bf16x8 aq0 = *(const bf16x8*)(qptr);
  bf16x8 aq1 = *(const bf16x8*)(qptr + 32);

  float lsum[4] = {0.f, 0.f, 0.f, 0.f};
  f32x4 acc[4] = {};

  int tmax_w = qb + 16 * wsub + 16;  // analytic tail starts here for this wave

  int grow = tid >> 3, gch = tid & 7;
  int sch = ((gch ^ (grow & 7)) << 3);
  const bf16* Kg = Kb + ((size_t)(b * S_LEN) + grow) * DMODEL + h * 64 + sch;
  const bf16* Vg = Vt + ((size_t)(bh * 64) + grow) * S_LEN + sch;
  int sdst = w * 1024;  // wave-uniform LDS dest (lane*16 implicit)

  int sw0 = (lg ^ (lr & 7)) << 4;
  int sw4 = sw0 ^ 0x40;
  char* plb = (char*)pl[w];

  GLDS(Kg, (char*)kl[0] + sdst);
  GLDS(Vg, (char*)vl[0] + sdst);
  asm volatile("s_waitcnt vmcnt(0)" ::: "memory");
  __syncthreads();

  int cur = 0;
  for (int it = 0; it < nt; ++it) {
    int t0 = it << 6;
    if (it + 1 < nt) {
      GLDS(Kg + (size_t)(t0 + 64) * DMODEL, (char*)kl[cur ^ 1] + sdst);
      GLDS(Vg + (t0 + 64), (char*)vl[cur ^ 1] + sdst);
    }
    if (t0 < tmax_w) {  // wave-uniform skip of fully-masked tiles
      char* klb = (char*)kl[cur];
      char* vlb = (char*)vl[cur];

      f32x4 sfrag[4];
      const f32x4 fz = {0.f, 0.f, 0.f, 0.f};
      __builtin_amdgcn_s_setprio(1);
#pragma unroll
      for (int c = 0; c < 4; ++c) {
        int rb = (16 * c + lr) * 128;
        bf16x8 bk0 = *(const bf16x8*)(klb + rb + sw0);
        bf16x8 bk1 = *(const bf16x8*)(klb + rb + sw4);
        f32x4 t = __builtin_amdgcn_mfma_f32_16x16x32_bf16(aq0, bk0, fz, 0, 0, 0);
        sfrag[c] = __builtin_amdgcn_mfma_f32_16x16x32_bf16(aq1, bk1, t, 0, 0, 0);
      }
      __builtin_amdgcn_s_setprio(0);

      if (t0 + 64 <= qb + 16 * wsub) {
#pragma unroll
        for (int r = 0; r < 4; ++r) {
          int row = lg * 4 + r;
          int pbase = row * 128 + ((lr & 7) << 1);
          int xorv = row & 7;
          float psum = 0.f;
#pragma unroll
          for (int c = 0; c < 4; ++c) {
            float pv = exp2f(sfrag[c][r]);
            psum += pv;
            int chunk = 2 * c + (lr >> 3);
            *(bf16*)(plb + pbase + (((chunk ^ xorv) << 4))) = (bf16)pv;
          }
          lsum[r] += psum;
        }
      } else {
#pragma unroll
        for (int r = 0; r < 4; ++r) {
          int sg = qb + 16 * wsub + lg * 4 + r;
          int row = lg * 4 + r;
          int pbase = row * 128 + ((lr & 7) << 1);
          int xorv = row & 7;
          float psum = 0.f;
#pragma unroll
          for (int c = 0; c < 4; ++c) {
            int tg = t0 + 16 * c + lr;
            float x = (tg <= sg) ? sfrag[c][r] : ((tg < tmax_w) ? 0.f : -1e30f);
            float pv = exp2f(x);
            psum += pv;
            int chunk = 2 * c + (lr >> 3);
            *(bf16*)(plb + pbase + (((chunk ^ xorv) << 4))) = (bf16)pv;
          }
          lsum[r] += psum;
        }
      }

      bf16x8 pa0 = *(const bf16x8*)(plb + lr * 128 + sw0);
      bf16x8 pa1 = *(const bf16x8*)(plb + lr * 128 + sw4);
      __builtin_amdgcn_s_setprio(1);
#pragma unroll
      for (int c = 0; c < 4; ++c) {
        int rb = (16 * c + lr) * 128;
        bf16x8 bv0 = *(const bf16x8*)(vlb + rb + sw0);
        bf16x8 bv1 = *(const bf16x8*)(vlb + rb + sw4);
        acc[c] = __builtin_amdgcn_mfma_f32_16x16x32_bf16(pa0, bv0, acc[c], 0, 0, 0);
        acc[c] = __builtin_amdgcn_mfma_f32_16x16x32_bf16(pa1, bv1, acc[c], 0, 0, 0);
      }
      __builtin_amdgcn_s_setprio(0);
    }
    asm volatile("s_waitcnt vmcnt(0)" ::: "memory");
    __syncthreads();
    cur ^= 1;
  }

#pragma unroll
  for (int r = 0; r < 4; ++r) {
#pragma unroll
    for (int d = 1; d < 16; d <<= 1) lsum[r] += __shfl_xor(lsum[r], d, 64);
  }

  int j16 = tmax_w >> 4;
  const float* suf = SUF + ((size_t)bh * 129 + j16) * 64;
  float cnt = (float)(S_LEN - tmax_w);
  float sufe[4];
#pragma unroll
  for (int c = 0; c < 4; ++c) sufe[c] = suf[16 * c + lr];
#pragma unroll
  for (int r = 0; r < 4; ++r) {
    float inv = 1.f / (lsum[r] + cnt);
    int sg = qb + 16 * wsub + lg * 4 + r;
#pragma unroll
    for (int c = 0; c < 4; ++c) {
      float o = (acc[c][r] + sufe[c]) * inv;
      attO[((size_t)(b * S_LEN) + sg) * DMODEL + h * 64 + 16 * c + lr] = (bf16)o;
    }
  }
}

__global__ __launch_bounds__(256) void ln_kernel(const bf16* __restrict__ x,
                                                 const float* __restrict__ gamma,
                                                 const float* __restrict__ beta,
                                                 float* __restrict__ out) {
  int row = blockIdx.x * 4 + (threadIdx.x >> 6);
  int l = threadIdx.x & 63;
  bf16x8 xv = *(const bf16x8*)(x + (size_t)row * DMODEL + l * 8);
  float xf[8];
  float s = 0.f, s2 = 0.f;
#pragma unroll
  for (int k = 0; k < 8; ++k) {
    xf[k] = (float)xv[k];
    s += xf[k];
    s2 += xf[k] * xf[k];
  }
#pragma unroll
  for (int d = 1; d < 64; d <<= 1) {
    s += __shfl_xor(s, d, 64);
    s2 += __shfl_xor(s2, d, 64);
  }
  float mean = s * (1.f / 512.f);
  float var = s2 * (1.f / 512.f) - mean * mean;
  float rstd = rsqrtf(var + 1e-5f);
  const float4* g4 = reinterpret_cast<const float4*>(gamma) + l * 2;
  const float4* b4 = reinterpret_cast<const float4*>(beta) + l * 2;
  float4 g0 = g4[0], g1 = g4[1], bb0 = b4[0], bb1 = b4[1];
  float4 o0, o1;
  o0.x = (xf[0] - mean) * rstd * g0.x + bb0.x;
  o0.y = (xf[1] - mean) * rstd * g0.y + bb0.y;
  o0.z = (xf[2] - mean) * rstd * g0.z + bb0.z;
  o0.w = (xf[3] - mean) * rstd * g0.w + bb0.w;
  o1.x = (xf[4] - mean) * rstd * g1.x + bb1.x;
  o1.y = (xf[5] - mean) * rstd * g1.y + bb1.y;
  o1.z = (xf[6] - mean) * rstd * g1.z + bb1.z;
  o1.w = (xf[7] - mean) * rstd * g1.w + bb1.w;
  float4* orow = reinterpret_cast<float4*>(out + (size_t)row * DMODEL) + l * 2;
  orow[0] = o0;
  orow[1] = o1;
}

extern "C" void kernel_launch(void* const* d_in, const int* in_sizes, int n_in,
                              void* d_out, int out_size, void* d_ws, size_t ws_size,
                              hipStream_t stream) {
  const float* embed = (const float*)d_in[0];
  const float* Wq = (const float*)d_in[1];
  const float* bq = (const float*)d_in[2];
  const float* Wk = (const float*)d_in[3];
  const float* bk = (const float*)d_in[4];
  const float* Wv = (const float*)d_in[5];
  const float* bv = (const float*)d_in[6];
  const float* Wo = (const float*)d_in[7];
  const float* bo = (const float*)d_in[8];
  const float* gamma = (const float*)d_in[9];
  const float* beta = (const float*)d_in[10];
  float* out = (float*)d_out;

  char* ws = (char*)d_ws;
  size_t off = 0;
  auto alc = [&](size_t b) { size_t o = off; off += (b + 255) & ~(size_t)255; return o; };
  bf16* Wqkv  = (bf16*)(ws + alc(1536ull * 512 * 2));
  bf16* Wob   = (bf16*)(ws + alc(512ull * 512 * 2));
  bf16* Qb    = (bf16*)(ws + alc(8192ull * 512 * 2));
  bf16* Kb    = (bf16*)(ws + alc(8192ull * 512 * 2));
  bf16* Vt    = (bf16*)(ws + alc(8192ull * 512 * 2));
  float* SUF  = (float*)(ws + alc(32ull * 129 * 64 * 4));
  bf16* AttO  = (bf16*)(ws + alc(8192ull * 512 * 2));
  bf16* Xb    = (bf16*)(ws + alc(8192ull * 512 * 2));
  (void)ws_size; (void)n_in; (void)in_sizes; (void)out_size;

  cast_w<<<dim3(256, 4), 256, 0, stream>>>(
      Wq, Wk, Wv, Wo, Wqkv, Wqkv + 512ull * 512, Wqkv + 1024ull * 512, Wob);

  gemm_qkv<<<dim3(64, 12), 256, 0, stream>>>(embed, Wqkv, bq, bk, bv, Qb, Kb, Vt);
  suf_kernel<<<256, 256, 0, stream>>>(Vt, SUF);
  flash_attn<<<dim3(16, 32), 512, 0, stream>>>(Qb, Kb, Vt, SUF, AttO);
  gemm_wo<<<dim3(64, 4), 256, 0, stream>>>(AttO, Wob, bo, embed, Xb);
  ln_kernel<<<2048, 256, 0, stream>>>(Xb, gamma, beta, out);
}

// Round 12
// 106.534 us; speedup vs baseline: 1.2416x; 1.0560x over previous
//
#include <hip/hip_runtime.h>
#include <hip/hip_bf16.h>

// B=4, S=2048, D=512, H=8, DH=64
// GEMMs: m97-structure 128x128 LDS-staged (GLDS w16 + XOR swizzle), bf16 A+B.
// flash: v4 structure (proven 53us, 0 conflicts) + 3-buffer 2-ahead prefetch with
// counted vmcnt(2) (T4: never drain to 0 in main loop). Flat softmax via exp2
// (tril zeros pin max~0); masked tail via V suffix sums.

typedef __bf16 bf16;
typedef __bf16 bf16x8 __attribute__((ext_vector_type(8)));
typedef __bf16 bf16x4v __attribute__((ext_vector_type(4)));
typedef float f32x4 __attribute__((ext_vector_type(4)));

#define S_LEN 2048
#define DMODEL 512
// log2(e)/sqrt(512): Q pre-scale so softmax exp is a bare exp2
#define QSCALE 0.06375870914f

#define GLDS(g, l) __builtin_amdgcn_global_load_lds(                  \
    (const __attribute__((address_space(1))) void*)(g),               \
    (__attribute__((address_space(3))) void*)(l), 16, 0, 0)

// One launch: embed (1,048,576 f4) then Wq,Wk,Wv,Wo (65,536 f4 each).
__global__ __launch_bounds__(256) void cast_all(
    const float* __restrict__ embed, const float* __restrict__ Wq,
    const float* __restrict__ Wk, const float* __restrict__ Wv,
    const float* __restrict__ Wo,
    bf16* __restrict__ Eb, bf16* __restrict__ Wqkv, bf16* __restrict__ Wob) {
  int i = blockIdx.x * 256 + threadIdx.x;
  const float* src;
  bf16* dst;
  int il;
  if (i < 1048576) {
    src = embed; dst = Eb; il = i;
  } else {
    int j = i - 1048576;
    int w = j >> 16;
    il = j & 65535;
    src = (w == 0) ? Wq : (w == 1) ? Wk : (w == 2) ? Wv : Wo;
    dst = (w == 3) ? Wob : Wqkv + (size_t)w * 262144;
  }
  float4 v = reinterpret_cast<const float4*>(src)[il];
  bf16x4v o;
  o[0] = (bf16)v.x; o[1] = (bf16)v.y; o[2] = (bf16)v.z; o[3] = (bf16)v.w;
  *reinterpret_cast<bf16x4v*>(dst + (size_t)il * 4) = o;
}

// ---- 128x128 tile GEMM core: C = A[M,512] * Bw[N,512]^T, K=512, BK=64 ----
__device__ __forceinline__ void gemm128_core(
    const bf16* __restrict__ A, const bf16* __restrict__ Bw,
    int row0, int col0, bf16* As, bf16* Bs, f32x4 (&acc)[4][4]) {
  int tid = threadIdx.x;
  int w = tid >> 6, l = tid & 63, lr = l & 15, lg = l >> 4;
  int wr = w >> 1, wc = w & 1;

  int srow = w * 8 + (l >> 3);
  int scol = ((l & 7) ^ (srow & 7)) << 3;
  const bf16* ga = A + (size_t)(row0 + srow) * DMODEL + scol;
  const bf16* gb = Bw + (size_t)(col0 + srow) * DMODEL + scol;
  char* asb = (char*)As;
  char* bsb = (char*)Bs;
  int sbase = w * 1024;

  int aoff[4], boff[4];
#pragma unroll
  for (int m = 0; m < 4; ++m) {
    aoff[m] = (wr * 64 + m * 16 + lr) * 128 + (((lg ^ (lr & 7))) << 4);
    boff[m] = (wc * 64 + m * 16 + lr) * 128 + (((lg ^ (lr & 7))) << 4);
  }

  for (int k0 = 0; k0 < DMODEL; k0 += 64) {
#pragma unroll
    for (int qt = 0; qt < 4; ++qt) {
      GLDS(ga + (size_t)qt * 32 * DMODEL, asb + qt * 4096 + sbase);
      GLDS(gb + (size_t)qt * 32 * DMODEL, bsb + qt * 4096 + sbase);
    }
    ga += 64; gb += 64;
    __syncthreads();

    bf16x8 af[2][4], bfv[2][4];
#pragma unroll
    for (int m = 0; m < 4; ++m) {
      af[0][m] = *(const bf16x8*)(asb + aoff[m]);
      af[1][m] = *(const bf16x8*)(asb + (aoff[m] ^ 0x40));
      bfv[0][m] = *(const bf16x8*)(bsb + boff[m]);
      bfv[1][m] = *(const bf16x8*)(bsb + (boff[m] ^ 0x40));
    }
#pragma unroll
    for (int m = 0; m < 4; ++m)
#pragma unroll
      for (int n = 0; n < 4; ++n) {
        acc[m][n] = __builtin_amdgcn_mfma_f32_16x16x32_bf16(af[0][m], bfv[0][n], acc[m][n], 0, 0, 0);
        acc[m][n] = __builtin_amdgcn_mfma_f32_16x16x32_bf16(af[1][m], bfv[1][n], acc[m][n], 0, 0, 0);
      }
    __syncthreads();
  }
}

// Fused QKV GEMM: Wqkv[1536][512]; col-tiles 0-3 = Q, 4-7 = K, 8-11 = V.
__global__ __launch_bounds__(256) void gemm_qkv(
    const bf16* __restrict__ A, const bf16* __restrict__ Wqkv,
    const float* __restrict__ bq, const float* __restrict__ bk, const float* __restrict__ bv,
    bf16* __restrict__ Qb, bf16* __restrict__ Kb, bf16* __restrict__ Vt) {
  __shared__ __align__(16) bf16 As[128 * 64];
  __shared__ __align__(16) bf16 Bs[128 * 64];
  int row0 = blockIdx.x * 128, col0 = blockIdx.y * 128;
  f32x4 acc[4][4] = {};
  gemm128_core(A, Wqkv, row0, col0, As, Bs, acc);

  int tid = threadIdx.x;
  int w = tid >> 6, l = tid & 63, lr = l & 15, lg = l >> 4;
  int wr = w >> 1, wc = w & 1;
  int z2 = col0 >> 9;  // 0=Q 1=K 2=V (uniform per block)
  if (z2 < 2) {
    bf16* O = z2 ? Kb : Qb;
    const float* bias = z2 ? bk : bq;
    float qs = z2 ? 1.0f : QSCALE;
#pragma unroll
    for (int n = 0; n < 4; ++n) {
      int cg = (col0 & 511) + wc * 64 + n * 16 + lr;
      float bi = bias[cg];
#pragma unroll
      for (int m = 0; m < 4; ++m) {
        int rg = row0 + wr * 64 + m * 16 + lg * 4;
#pragma unroll
        for (int r = 0; r < 4; ++r)
          O[(size_t)(rg + r) * DMODEL + cg] = (bf16)((acc[m][n][r] + bi) * qs);
      }
    }
  } else {
    // V: store transposed Vt[b][h][e][s]
#pragma unroll
    for (int n = 0; n < 4; ++n) {
      int ep = (col0 & 511) + wc * 64 + n * 16 + lr;
      int h = ep >> 6, e = ep & 63;
      float bi = bv[ep];
#pragma unroll
      for (int m = 0; m < 4; ++m) {
        int rg = row0 + wr * 64 + m * 16 + lg * 4;
        int b = rg >> 11, s0 = rg & 2047;
        bf16x4v pk;
#pragma unroll
        for (int r = 0; r < 4; ++r) pk[r] = (bf16)(acc[m][n][r] + bi);
        *(bf16x4v*)(Vt + ((size_t)((b * 8 + h) * 64 + e)) * S_LEN + s0) = pk;
      }
    }
  }
}

// Wo GEMM + bias + residual, bf16 out (LN reads bf16).
__global__ __launch_bounds__(256) void gemm_wo(
    const bf16* __restrict__ A, const bf16* __restrict__ W,
    const float* __restrict__ bo, const float* __restrict__ embed,
    bf16* __restrict__ X) {
  __shared__ __align__(16) bf16 As[128 * 64];
  __shared__ __align__(16) bf16 Bs[128 * 64];
  int row0 = blockIdx.x * 128, col0 = blockIdx.y * 128;
  f32x4 acc[4][4] = {};
  gemm128_core(A, W, row0, col0, As, Bs, acc);

  int tid = threadIdx.x;
  int w = tid >> 6, l = tid & 63, lr = l & 15, lg = l >> 4;
  int wr = w >> 1, wc = w & 1;
#pragma unroll
  for (int n = 0; n < 4; ++n) {
    int cg = col0 + wc * 64 + n * 16 + lr;
    float bi = bo[cg];
#pragma unroll
    for (int m = 0; m < 4; ++m) {
      int rg = row0 + wr * 64 + m * 16 + lg * 4;
#pragma unroll
      for (int r = 0; r < 4; ++r)
        X[(size_t)(rg + r) * DMODEL + cg] =
            (bf16)(acc[m][n][r] + bi + embed[(size_t)(rg + r) * DMODEL + cg]);
    }
  }
}

// SUF[bh][j][e] = sum_{t >= 16j} V[t][e], j = 0..128 (SUF[128]=0).
// 256 blocks: (bh, e-group of 8); 256 thr = (el 0..7, seg 0..31), 4 chunks/seg.
__global__ __launch_bounds__(256) void suf_kernel(const bf16* __restrict__ Vt,
                                                  float* __restrict__ SUF) {
  int bh = blockIdx.x >> 3;
  int eg = blockIdx.x & 7;
  int el = threadIdx.x & 7;
  int seg = threadIdx.x >> 3;  // 0..31
  int e = eg * 8 + el;
  __shared__ float segtot[32][9];
  const bf16* vrow = Vt + ((size_t)bh * 64 + e) * S_LEN;
  float loc[4];
  float carry = 0.f;
#pragma unroll
  for (int j = 3; j >= 0; --j) {
    int jj = seg * 4 + j;
    bf16x8 a = *(const bf16x8*)(vrow + jj * 16);
    bf16x8 b2 = *(const bf16x8*)(vrow + jj * 16 + 8);
    float s = 0.f;
#pragma unroll
    for (int k = 0; k < 8; ++k) s += (float)a[k] + (float)b2[k];
    carry += s;
    loc[j] = carry;
  }
  segtot[seg][el] = carry;
  __syncthreads();
  float add = 0.f;
  for (int s2 = seg + 1; s2 < 32; ++s2) add += segtot[s2][el];
  float* srow = SUF + (size_t)bh * 129 * 64 + e;
#pragma unroll
  for (int j = 0; j < 4; ++j) srow[(size_t)(seg * 4 + j) * 64] = loc[j] + add;
  if (seg == 0) srow[(size_t)128 * 64] = 0.f;
}

// Flash attention: v4 structure + 3-buffer 2-ahead counted-vmcnt prefetch.
// 8 waves, waves 0-3 = big q-tile (16+p), waves 4-7 = small q-tile (15-p), one
// shared KV sweep (nt=17+p), flat softmax via bare exp2, setprio on MFMA.
__global__ __launch_bounds__(512) void flash_attn(
    const bf16* __restrict__ Qb, const bf16* __restrict__ Kb,
    const bf16* __restrict__ Vt, const float* __restrict__ SUF,
    bf16* __restrict__ attO) {
  int bh = blockIdx.y;
  int b = bh >> 3, h = bh & 7;
  int p = (int)gridDim.x - 1 - (int)blockIdx.x;  // 15..0, biggest first
  int tid = threadIdx.x;
  int w = tid >> 6, l = tid & 63, lr = l & 15, lg = l >> 4;
  int wsub = w & 3;
  int qtile = (w < 4) ? (16 + p) : (15 - p);
  int qb = qtile * 64;
  int nt = 17 + p;  // block-uniform KV-tile count (covers big tile's range)

  __shared__ __align__(16) bf16 kl[3][64 * 64];   // K tiles [t][e], swizzled
  __shared__ __align__(16) bf16 vl[3][64 * 64];   // V^T tiles [e][t], swizzled
  __shared__ __align__(16) bf16 pl[8][16 * 64];   // per-wave P tile [s][t], swizzled

  int srow = qb + 16 * wsub + lr;
  const bf16* qptr = Qb + ((size_t)(b * S_LEN) + srow) * DMODEL + h * 64 + lg * 8;
  bf16x8 aq0 = *(const bf16x8*)(qptr);
  bf16x8 aq1 = *(const bf16x8*)(qptr + 32);

  float lsum[4] = {0.f, 0.f, 0.f, 0.f};
  f32x4 acc[4] = {};

  int tmax_w = qb + 16 * wsub + 16;  // analytic tail starts here for this wave

  int grow = tid >> 3, gch = tid & 7;
  int sch = ((gch ^ (grow & 7)) << 3);
  const bf16* Kg = Kb + ((size_t)(b * S_LEN) + grow) * DMODEL + h * 64 + sch;
  const bf16* Vg = Vt + ((size_t)(bh * 64) + grow) * S_LEN + sch;
  int sdst = w * 1024;  // wave-uniform LDS dest (lane*16 implicit)

  int sw0 = (lg ^ (lr & 7)) << 4;
  int sw4 = sw0 ^ 0x40;
  char* plb = (char*)pl[w];

  // prologue: stage tiles 0 and 1; wait only for tile 0 (vmcnt(2) leaves
  // tile 1's 2 per-thread ops in flight)
  GLDS(Kg, (char*)kl[0] + sdst);
  GLDS(Vg, (char*)vl[0] + sdst);
  GLDS(Kg + (size_t)64 * DMODEL, (char*)kl[1] + sdst);
  GLDS(Vg + 64, (char*)vl[1] + sdst);
  asm volatile("s_waitcnt vmcnt(2)" ::: "memory");
  __syncthreads();

  int cur = 0;
  for (int it = 0; it < nt; ++it) {
    int t0 = it << 6;
    bool more = (it + 2 < nt);
    if (more) {
      int stg = cur + 2; if (stg >= 3) stg -= 3;
      GLDS(Kg + (size_t)(t0 + 128) * DMODEL, (char*)kl[stg] + sdst);
      GLDS(Vg + (t0 + 128), (char*)vl[stg] + sdst);
    }
    if (t0 < tmax_w) {  // wave-uniform skip of fully-masked tiles
      char* klb = (char*)kl[cur];
      char* vlb = (char*)vl[cur];

      f32x4 sfrag[4];
      const f32x4 fz = {0.f, 0.f, 0.f, 0.f};
      __builtin_amdgcn_s_setprio(1);
#pragma unroll
      for (int c = 0; c < 4; ++c) {
        int rb = (16 * c + lr) * 128;
        bf16x8 bk0 = *(const bf16x8*)(klb + rb + sw0);
        bf16x8 bk1 = *(const bf16x8*)(klb + rb + sw4);
        f32x4 t = __builtin_amdgcn_mfma_f32_16x16x32_bf16(aq0, bk0, fz, 0, 0, 0);
        sfrag[c] = __builtin_amdgcn_mfma_f32_16x16x32_bf16(aq1, bk1, t, 0, 0, 0);
      }
      __builtin_amdgcn_s_setprio(0);

      if (t0 + 64 <= qb + 16 * wsub) {
#pragma unroll
        for (int r = 0; r < 4; ++r) {
          int row = lg * 4 + r;
          int pbase = row * 128 + ((lr & 7) << 1);
          int xorv = row & 7;
          float psum = 0.f;
#pragma unroll
          for (int c = 0; c < 4; ++c) {
            float pv = exp2f(sfrag[c][r]);
            psum += pv;
            int chunk = 2 * c + (lr >> 3);
            *(bf16*)(plb + pbase + (((chunk ^ xorv) << 4))) = (bf16)pv;
          }
          lsum[r] += psum;
        }
      } else {
#pragma unroll
        for (int r = 0; r < 4; ++r) {
          int sg = qb + 16 * wsub + lg * 4 + r;
          int row = lg * 4 + r;
          int pbase = row * 128 + ((lr & 7) << 1);
          int xorv = row & 7;
          float psum = 0.f;
#pragma unroll
          for (int c = 0; c < 4; ++c) {
            int tg = t0 + 16 * c + lr;
            float x = (tg <= sg) ? sfrag[c][r] : ((tg < tmax_w) ? 0.f : -1e30f);
            float pv = exp2f(x);
            psum += pv;
            int chunk = 2 * c + (lr >> 3);
            *(bf16*)(plb + pbase + (((chunk ^ xorv) << 4))) = (bf16)pv;
          }
          lsum[r] += psum;
        }
      }

      bf16x8 pa0 = *(const bf16x8*)(plb + lr * 128 + sw0);
      bf16x8 pa1 = *(const bf16x8*)(plb + lr * 128 + sw4);
      __builtin_amdgcn_s_setprio(1);
#pragma unroll
      for (int c = 0; c < 4; ++c) {
        int rb = (16 * c + lr) * 128;
        bf16x8 bv0 = *(const bf16x8*)(vlb + rb + sw0);
        bf16x8 bv1 = *(const bf16x8*)(vlb + rb + sw4);
        acc[c] = __builtin_amdgcn_mfma_f32_16x16x32_bf16(pa0, bv0, acc[c], 0, 0, 0);
        acc[c] = __builtin_amdgcn_mfma_f32_16x16x32_bf16(pa1, bv1, acc[c], 0, 0, 0);
      }
      __builtin_amdgcn_s_setprio(0);
    }
    // counted wait: force tile it+1 complete; allow tile it+2's 2 ops in flight
    if (more) {
      asm volatile("s_waitcnt vmcnt(2)" ::: "memory");
    } else {
      asm volatile("s_waitcnt vmcnt(0)" ::: "memory");
    }
    __syncthreads();
    cur = (cur == 2) ? 0 : cur + 1;
  }

#pragma unroll
  for (int r = 0; r < 4; ++r) {
#pragma unroll
    for (int d = 1; d < 16; d <<= 1) lsum[r] += __shfl_xor(lsum[r], d, 64);
  }

  int j16 = tmax_w >> 4;
  const float* suf = SUF + ((size_t)bh * 129 + j16) * 64;
  float cnt = (float)(S_LEN - tmax_w);
  float sufe[4];
#pragma unroll
  for (int c = 0; c < 4; ++c) sufe[c] = suf[16 * c + lr];
#pragma unroll
  for (int r = 0; r < 4; ++r) {
    float inv = 1.f / (lsum[r] + cnt);
    int sg = qb + 16 * wsub + lg * 4 + r;
#pragma unroll
    for (int c = 0; c < 4; ++c) {
      float o = (acc[c][r] + sufe[c]) * inv;
      attO[((size_t)(b * S_LEN) + sg) * DMODEL + h * 64 + 16 * c + lr] = (bf16)o;
    }
  }
}

__global__ __launch_bounds__(256) void ln_kernel(const bf16* __restrict__ x,
                                                 const float* __restrict__ gamma,
                                                 const float* __restrict__ beta,
                                                 float* __restrict__ out) {
  int row = blockIdx.x * 4 + (threadIdx.x >> 6);
  int l = threadIdx.x & 63;
  bf16x8 xv = *(const bf16x8*)(x + (size_t)row * DMODEL + l * 8);
  float xf[8];
  float s = 0.f, s2 = 0.f;
#pragma unroll
  for (int k = 0; k < 8; ++k) {
    xf[k] = (float)xv[k];
    s += xf[k];
    s2 += xf[k] * xf[k];
  }
#pragma unroll
  for (int d = 1; d < 64; d <<= 1) {
    s += __shfl_xor(s, d, 64);
    s2 += __shfl_xor(s2, d, 64);
  }
  float mean = s * (1.f / 512.f);
  float var = s2 * (1.f / 512.f) - mean * mean;
  float rstd = rsqrtf(var + 1e-5f);
  const float4* g4 = reinterpret_cast<const float4*>(gamma) + l * 2;
  const float4* b4 = reinterpret_cast<const float4*>(beta) + l * 2;
  float4 g0 = g4[0], g1 = g4[1], bb0 = b4[0], bb1 = b4[1];
  float4 o0, o1;
  o0.x = (xf[0] - mean) * rstd * g0.x + bb0.x;
  o0.y = (xf[1] - mean) * rstd * g0.y + bb0.y;
  o0.z = (xf[2] - mean) * rstd * g0.z + bb0.z;
  o0.w = (xf[3] - mean) * rstd * g0.w + bb0.w;
  o1.x = (xf[4] - mean) * rstd * g1.x + bb1.x;
  o1.y = (xf[5] - mean) * rstd * g1.y + bb1.y;
  o1.z = (xf[6] - mean) * rstd * g1.z + bb1.z;
  o1.w = (xf[7] - mean) * rstd * g1.w + bb1.w;
  float4* orow = reinterpret_cast<float4*>(out + (size_t)row * DMODEL) + l * 2;
  orow[0] = o0;
  orow[1] = o1;
}

extern "C" void kernel_launch(void* const* d_in, const int* in_sizes, int n_in,
                              void* d_out, int out_size, void* d_ws, size_t ws_size,
                              hipStream_t stream) {
  const float* embed = (const float*)d_in[0];
  const float* Wq = (const float*)d_in[1];
  const float* bq = (const float*)d_in[2];
  const float* Wk = (const float*)d_in[3];
  const float* bk = (const float*)d_in[4];
  const float* Wv = (const float*)d_in[5];
  const float* bv = (const float*)d_in[6];
  const float* Wo = (const float*)d_in[7];
  const float* bo = (const float*)d_in[8];
  const float* gamma = (const float*)d_in[9];
  const float* beta = (const float*)d_in[10];
  float* out = (float*)d_out;

  char* ws = (char*)d_ws;
  size_t off = 0;
  auto alc = [&](size_t b) { size_t o = off; off += (b + 255) & ~(size_t)255; return o; };
  bf16* Eb    = (bf16*)(ws + alc(8192ull * 512 * 2));
  bf16* Wqkv  = (bf16*)(ws + alc(1536ull * 512 * 2));
  bf16* Wob   = (bf16*)(ws + alc(512ull * 512 * 2));
  bf16* Qb    = (bf16*)(ws + alc(8192ull * 512 * 2));
  bf16* Kb    = (bf16*)(ws + alc(8192ull * 512 * 2));
  bf16* Vt    = (bf16*)(ws + alc(8192ull * 512 * 2));
  float* SUF  = (float*)(ws + alc(32ull * 129 * 64 * 4));
  bf16* AttO  = (bf16*)(ws + alc(8192ull * 512 * 2));
  bf16* Xb    = (bf16*)(ws + alc(8192ull * 512 * 2));
  (void)ws_size; (void)n_in; (void)in_sizes; (void)out_size;

  cast_all<<<5120, 256, 0, stream>>>(embed, Wq, Wk, Wv, Wo, Eb, Wqkv, Wob);

  gemm_qkv<<<dim3(64, 12), 256, 0, stream>>>(Eb, Wqkv, bq, bk, bv, Qb, Kb, Vt);
  suf_kernel<<<256, 256, 0, stream>>>(Vt, SUF);
  flash_attn<<<dim3(16, 32), 512, 0, stream>>>(Qb, Kb, Vt, SUF, AttO);
  gemm_wo<<<dim3(64, 4), 256, 0, stream>>>(AttO, Wob, bo, embed, Xb);
  ln_kernel<<<2048, 256, 0, stream>>>(Xb, gamma, beta, out);
}